// Round 7
// baseline (252.378 us; speedup 1.0000x reference)
//
#include <hip/hip_runtime.h>
#include <cstdint>

// GATGraphRegressor: 2-layer GAT (4-head then 1-head) + global mean pool + linear.
// Structure:
//  - CSR over dst; degree-sorted node order via counting sort done ENTIRELY in
//    the single-block scan kernel with LDS cursors (global-atomic reorder was
//    a 54us same-line atomic drain).
//  - Edge softmax weights precomputed into [H][E] csr-order arrays (per-XCD
//    streaming footprint 1.28MB, not 5MB) fused into the CSR fill pass.
//  - Aggregation: XCD-pinned channel slices (block b -> slice b&7); 8 equal-
//    degree nodes/wave, lane owns 4 channels; nontemporal loads for streams.
//  - Attention scores fused into SGEMM epilogue (each 64-col block = 1 head).

__device__ __forceinline__ float leaky02(float x) { return x > 0.f ? x : 0.2f * x; }
__device__ __forceinline__ float eluf(float x) { return x > 0.f ? x : expm1f(x); }

// ---------------- CSR count ----------------
__global__ void count_kernel(const int* __restrict__ dst, int* __restrict__ cnt, int E) {
    int e = blockIdx.x * blockDim.x + threadIdx.x;
    if (e < E) atomicAdd(&cnt[dst[e]], 1);
}

constexpr int SCAN_CHUNK = 20;  // 1024*20 = 20480 >= N=20000
// scan of cnt -> row_ptr; degree-histogram counting sort -> order[] (all in-block).
__global__ __launch_bounds__(1024) void scan_kernel(const int* __restrict__ cnt,
                                                    int* __restrict__ row_ptr,
                                                    int* __restrict__ order, int N) {
    __shared__ int lds[1024];
    __shared__ int hbin[64];
    __shared__ int binbase[64];
    const int tid = threadIdx.x;
    if (tid < 64) hbin[tid] = 0;
    __syncthreads();
    int c[SCAN_CHUNK];
    const int base = tid * SCAN_CHUNK;
    int loc = 0;
#pragma unroll
    for (int i = 0; i < SCAN_CHUNK; i++) {
        int idx = base + i;
        int v = (idx < N) ? cnt[idx] : 0;
        c[i] = v;
        loc += v;
        if (idx < N) atomicAdd(&hbin[min(v, 63)], 1);
    }
    lds[tid] = loc;
    __syncthreads();
    for (int off = 1; off < 1024; off <<= 1) {
        int v = (tid >= off) ? lds[tid - off] : 0;
        __syncthreads();
        lds[tid] += v;
        __syncthreads();
    }
    int run = (tid > 0) ? lds[tid - 1] : 0;
#pragma unroll
    for (int i = 0; i < SCAN_CHUNK; i++) {
        int idx = base + i;
        if (idx < N) row_ptr[idx] = run;
        run += c[i];
    }
    if (tid == 1023) row_ptr[N] = run;
    // exclusive scan of 64 degree bins (wave 0), reset cursors
    if (tid < 64) {
        int v = hbin[tid];
        int s = v;
#pragma unroll
        for (int off = 1; off < 64; off <<= 1) {
            int o = __shfl_up(s, off);
            if (tid >= off) s += o;
        }
        binbase[tid] = s - v;
        hbin[tid] = 0;  // reuse as cursor
    }
    __syncthreads();
    // counting-sort scatter via LDS cursors
#pragma unroll
    for (int i = 0; i < SCAN_CHUNK; i++) {
        int idx = base + i;
        if (idx < N) {
            int b = min(c[i], 63);
            int r = atomicAdd(&hbin[b], 1);
            order[binbase[b] + r] = idx;
        }
    }
}

// ---------------- CSR fill + conv1 edge weights ([H][E] layout) ----------------
__global__ void fill_ew4_kernel(const int* __restrict__ src, const int* __restrict__ dst,
                                const int* __restrict__ row_ptr, int* __restrict__ cursor,
                                int* __restrict__ col, int* __restrict__ pos,
                                const float* __restrict__ sS, const float* __restrict__ dS,
                                float* __restrict__ wcsr, int E) {
    int e = blockIdx.x * blockDim.x + threadIdx.x;
    if (e >= E) return;
    int s = src[e], d = dst[e];
    int p = row_ptr[d] + atomicAdd(&cursor[d], 1);
    col[p] = s;
    pos[e] = p;
    float4 sv = *(const float4*)&sS[s * 4];
    float4 dv = *(const float4*)&dS[d * 4];
    wcsr[p]         = __expf(leaky02(sv.x + dv.x));
    wcsr[E + p]     = __expf(leaky02(sv.y + dv.y));
    wcsr[2 * E + p] = __expf(leaky02(sv.z + dv.z));
    wcsr[3 * E + p] = __expf(leaky02(sv.w + dv.w));
}

__global__ void edge_w1_kernel(const int* __restrict__ src, const int* __restrict__ dst,
                               const int* __restrict__ pos, const float* __restrict__ sS,
                               const float* __restrict__ dS, float* __restrict__ wcsr, int E) {
    int e = blockIdx.x * blockDim.x + threadIdx.x;
    if (e >= E) return;
    wcsr[pos[e]] = __expf(leaky02(sS[src[e]] + dS[dst[e]]));
}

// ---------------- SGEMM + fused per-node scores ----------------
template <int H>
__global__ __launch_bounds__(256) void sgemm_scores_kernel(
    const float* __restrict__ A, const float* __restrict__ B, float* __restrict__ C,
    int M, int K, const float* __restrict__ asrc, const float* __restrict__ adst,
    float* __restrict__ sS, float* __restrict__ dS, float* __restrict__ wself) {
    constexpr int Nc = H * 64;
    __shared__ __align__(16) float As[32][68];
    __shared__ __align__(16) float Bs[32][68];
    const int tid = threadIdx.x;
    const int bm = blockIdx.x * 64, bn = blockIdx.y * 64;
    const int ty = tid >> 4, tx = tid & 15;
    float acc[4][4] = {};
    for (int k0 = 0; k0 < K; k0 += 32) {
#pragma unroll
        for (int i = 0; i < 8; i++) {
            int idx = tid + i * 256;
            int m = idx >> 5, kk = idx & 31;
            int gm = bm + m;
            if (gm >= M) gm = 0;
            As[kk][m] = A[(size_t)gm * K + k0 + kk];
        }
#pragma unroll
        for (int i = 0; i < 8; i++) {
            int idx = tid + i * 256;
            int kk = idx >> 6, n = idx & 63;
            Bs[kk][n] = B[(size_t)(k0 + kk) * Nc + bn + n];
        }
        __syncthreads();
#pragma unroll
        for (int kk = 0; kk < 32; kk++) {
            float4 a4 = *(const float4*)&As[kk][ty * 4];
            float4 b4 = *(const float4*)&Bs[kk][tx * 4];
            float av[4] = {a4.x, a4.y, a4.z, a4.w};
            float bv[4] = {b4.x, b4.y, b4.z, b4.w};
#pragma unroll
            for (int r = 0; r < 4; r++)
#pragma unroll
                for (int c2 = 0; c2 < 4; c2++) acc[r][c2] += av[r] * bv[c2];
        }
        __syncthreads();
    }
    const int h = bn >> 6;
    float sr[4], dr[4];
#pragma unroll
    for (int r = 0; r < 4; r++) {
        float s = 0.f, d = 0.f;
#pragma unroll
        for (int c2 = 0; c2 < 4; c2++) {
            float hv = acc[r][c2];
            s += hv * asrc[h * 64 + tx * 4 + c2];
            d += hv * adst[h * 64 + tx * 4 + c2];
        }
        sr[r] = s;
        dr[r] = d;
    }
#pragma unroll
    for (int off = 1; off <= 8; off <<= 1) {
#pragma unroll
        for (int r = 0; r < 4; r++) {
            sr[r] += __shfl_xor(sr[r], off);
            dr[r] += __shfl_xor(dr[r], off);
        }
    }
#pragma unroll
    for (int r = 0; r < 4; r++) {
        int gm = bm + ty * 4 + r;
        if (gm < M) {
            float4 o = make_float4(acc[r][0], acc[r][1], acc[r][2], acc[r][3]);
            *(float4*)&C[(size_t)gm * Nc + bn + tx * 4] = o;
            if (tx == 0) {
                sS[gm * H + h] = sr[r];
                dS[gm * H + h] = dr[r];
                wself[gm * H + h] = __expf(leaky02(sr[r] + dr[r]));
            }
        }
    }
}

// ---------------- conv1 aggregation: XCD-sliced, 8 equal-degree nodes/wave ------
__global__ __launch_bounds__(256) void gat_agg4_kernel(
    const float* __restrict__ hbuf, const float* __restrict__ wcsr,
    const float* __restrict__ wself, const int* __restrict__ row_ptr,
    const int* __restrict__ col, const int* __restrict__ order,
    const float* __restrict__ bias, float* __restrict__ out, int N, int E) {
    const int slice = blockIdx.x & 7;
    const int lane = threadIdx.x & 63;
    const int cq = lane & 7;
    const int vidx = (blockIdx.x >> 3) * 32 + (threadIdx.x >> 6) * 8 + (lane >> 3);
    const bool valid = vidx < N;
    const int v = order[min(vidx, N - 1)];
    const int cbase = slice * 32 + cq * 4;
    const int hh = slice >> 1;
    const float* __restrict__ wch = wcsr + (size_t)hh * E;
    const int begin = row_ptr[v], end = row_ptr[v + 1];
    float w = wself[v * 4 + hh];
    float den = w;
    float4 hv = *(const float4*)&hbuf[(size_t)v * 256 + cbase];
    float4 acc = make_float4(w * hv.x, w * hv.y, w * hv.z, w * hv.w);
    const int last = end - 1;
    for (int i = begin; i < end; i += 4) {
        int i1 = min(i + 1, last), i2 = min(i + 2, last), i3 = min(i + 3, last);
        int s0 = __builtin_nontemporal_load(&col[i]);
        int s1 = __builtin_nontemporal_load(&col[i1]);
        int s2 = __builtin_nontemporal_load(&col[i2]);
        int s3 = __builtin_nontemporal_load(&col[i3]);
        float w0 = __builtin_nontemporal_load(&wch[i]);
        float w1 = __builtin_nontemporal_load(&wch[i1]);
        float w2 = __builtin_nontemporal_load(&wch[i2]);
        float w3 = __builtin_nontemporal_load(&wch[i3]);
        float4 h0 = *(const float4*)&hbuf[(size_t)s0 * 256 + cbase];
        float4 h1 = *(const float4*)&hbuf[(size_t)s1 * 256 + cbase];
        float4 h2 = *(const float4*)&hbuf[(size_t)s2 * 256 + cbase];
        float4 h3 = *(const float4*)&hbuf[(size_t)s3 * 256 + cbase];
        w1 = (i + 1 < end) ? w1 : 0.f;
        w2 = (i + 2 < end) ? w2 : 0.f;
        w3 = (i + 3 < end) ? w3 : 0.f;
        den += w0 + w1 + w2 + w3;
        acc.x += w0 * h0.x + w1 * h1.x + w2 * h2.x + w3 * h3.x;
        acc.y += w0 * h0.y + w1 * h1.y + w2 * h2.y + w3 * h3.y;
        acc.z += w0 * h0.z + w1 * h1.z + w2 * h2.z + w3 * h3.z;
        acc.w += w0 * h0.w + w1 * h1.w + w2 * h2.w + w3 * h3.w;
    }
    if (valid) {
        float4 b4 = *(const float4*)&bias[cbase];
        float inv = 1.f / den;
        float4 r;
        r.x = eluf(acc.x * inv + b4.x);
        r.y = eluf(acc.y * inv + b4.y);
        r.z = eluf(acc.z * inv + b4.z);
        r.w = eluf(acc.w * inv + b4.w);
        *(float4*)&out[(size_t)v * 256 + cbase] = r;
    }
}

// ---------------- conv2 aggregation (64ch) + Wlin dot, 2 slices ----------------
__global__ __launch_bounds__(256) void gat_agg1_kernel(
    const float* __restrict__ hbuf, const float* __restrict__ wcsr,
    const float* __restrict__ wself, const int* __restrict__ row_ptr,
    const int* __restrict__ col, const int* __restrict__ order,
    const float* __restrict__ bias, const float* __restrict__ Wlin,
    float* __restrict__ pn0, float* __restrict__ pn1, int N) {
    const int slice = blockIdx.x & 1;
    const int lane = threadIdx.x & 63;
    const int cq = lane & 7;
    const int vidx = (blockIdx.x >> 1) * 32 + (threadIdx.x >> 6) * 8 + (lane >> 3);
    const bool valid = vidx < N;
    const int v = order[min(vidx, N - 1)];
    const int cbase = slice * 32 + cq * 4;
    const int begin = row_ptr[v], end = row_ptr[v + 1];
    float w = wself[v];
    float den = w;
    float4 hv = *(const float4*)&hbuf[(size_t)v * 64 + cbase];
    float4 acc = make_float4(w * hv.x, w * hv.y, w * hv.z, w * hv.w);
    const int last = end - 1;
    for (int i = begin; i < end; i += 4) {
        int i1 = min(i + 1, last), i2 = min(i + 2, last), i3 = min(i + 3, last);
        int s0 = __builtin_nontemporal_load(&col[i]);
        int s1 = __builtin_nontemporal_load(&col[i1]);
        int s2 = __builtin_nontemporal_load(&col[i2]);
        int s3 = __builtin_nontemporal_load(&col[i3]);
        float w0 = __builtin_nontemporal_load(&wcsr[i]);
        float w1 = __builtin_nontemporal_load(&wcsr[i1]);
        float w2 = __builtin_nontemporal_load(&wcsr[i2]);
        float w3 = __builtin_nontemporal_load(&wcsr[i3]);
        float4 h0 = *(const float4*)&hbuf[(size_t)s0 * 64 + cbase];
        float4 h1 = *(const float4*)&hbuf[(size_t)s1 * 64 + cbase];
        float4 h2 = *(const float4*)&hbuf[(size_t)s2 * 64 + cbase];
        float4 h3 = *(const float4*)&hbuf[(size_t)s3 * 64 + cbase];
        w1 = (i + 1 < end) ? w1 : 0.f;
        w2 = (i + 2 < end) ? w2 : 0.f;
        w3 = (i + 3 < end) ? w3 : 0.f;
        den += w0 + w1 + w2 + w3;
        acc.x += w0 * h0.x + w1 * h1.x + w2 * h2.x + w3 * h3.x;
        acc.y += w0 * h0.y + w1 * h1.y + w2 * h2.y + w3 * h3.y;
        acc.z += w0 * h0.z + w1 * h1.z + w2 * h2.z + w3 * h3.z;
        acc.w += w0 * h0.w + w1 * h1.w + w2 * h2.w + w3 * h3.w;
    }
    float4 b4 = *(const float4*)&bias[cbase];
    float4 wl = *(const float4*)&Wlin[cbase];
    float inv = 1.f / den;
    float p = eluf(acc.x * inv + b4.x) * wl.x + eluf(acc.y * inv + b4.y) * wl.y +
              eluf(acc.z * inv + b4.z) * wl.z + eluf(acc.w * inv + b4.w) * wl.w;
    p += __shfl_xor(p, 1);
    p += __shfl_xor(p, 2);
    p += __shfl_xor(p, 4);
    if (valid && cq == 0) (slice ? pn1 : pn0)[v] = p;
}

// ---------------- finalize: one wave per graph, segmented sum over sorted batch ----
__global__ __launch_bounds__(64) void finalize_kernel(const float* __restrict__ pn0,
                                                      const float* __restrict__ pn1,
                                                      const int* __restrict__ batch,
                                                      const float* __restrict__ blin,
                                                      float* __restrict__ outp, int N, int G) {
    const int g = blockIdx.x;
    const int lane = threadIdx.x;
    int lo = 0, hi = N;
    while (lo < hi) { int mid = (lo + hi) >> 1; if (batch[mid] < g) lo = mid + 1; else hi = mid; }
    int lo2 = lo, hi2 = N;
    while (lo2 < hi2) { int mid = (lo2 + hi2) >> 1; if (batch[mid] < g + 1) lo2 = mid + 1; else hi2 = mid; }
    float s = 0.f;
    for (int i = lo + lane; i < hi2; i += 64) s += pn0[i] + pn1[i];
#pragma unroll
    for (int off = 32; off > 0; off >>= 1) s += __shfl_xor(s, off);
    if (lane == 0) {
        float cnt = (float)(hi2 - lo);
        outp[g] = s / fmaxf(cnt, 1.f) + blin[0];
    }
}

extern "C" void kernel_launch(void* const* d_in, const int* in_sizes, int n_in,
                              void* d_out, int out_size, void* d_ws, size_t ws_size,
                              hipStream_t stream) {
    const float* x      = (const float*)d_in[0];
    const int*   ei     = (const int*)d_in[1];
    const int*   batch  = (const int*)d_in[2];
    const float* W1     = (const float*)d_in[3];
    const float* a_src1 = (const float*)d_in[4];
    const float* a_dst1 = (const float*)d_in[5];
    const float* b1     = (const float*)d_in[6];
    const float* W2     = (const float*)d_in[7];
    const float* a_src2 = (const float*)d_in[8];
    const float* a_dst2 = (const float*)d_in[9];
    const float* b2     = (const float*)d_in[10];
    const float* Wlin   = (const float*)d_in[11];
    const float* blin   = (const float*)d_in[12];

    const int N = in_sizes[2];
    const int E = in_sizes[1] / 2;
    const int G = out_size;
    const int* src = ei;
    const int* dst = ei + E;

    char* ws = (char*)d_ws;
    size_t off = 0;
    auto carve = [&](size_t bytes) -> char* {
        char* p = ws + off;
        off = (off + bytes + 255) & ~(size_t)255;
        return p;
    };
    float* h1      = (float*)carve((size_t)N * 256 * 4);
    float* out1    = (float*)carve((size_t)N * 256 * 4);
    float* s1      = (float*)carve((size_t)N * 4 * 4);
    float* d1      = (float*)carve((size_t)N * 4 * 4);
    float* wself1  = (float*)carve((size_t)N * 4 * 4);
    float* s2      = (float*)carve((size_t)N * 4);
    float* d2      = (float*)carve((size_t)N * 4);
    float* wself2  = (float*)carve((size_t)N * 4);
    int*   row_ptr = (int*)carve((size_t)(N + 1) * 4);
    int*   cntcur  = (int*)carve((size_t)2 * N * 4);
    int*   col     = (int*)carve((size_t)E * 4);
    int*   pos     = (int*)carve((size_t)E * 4);
    float* wcsr1   = (float*)carve((size_t)E * 4 * 4);  // [H][E]
    float* wcsr2   = (float*)carve((size_t)E * 4);
    int*   order   = (int*)carve((size_t)N * 4);
    float* pn0     = (float*)carve((size_t)N * 4);
    float* pn1     = (float*)carve((size_t)N * 4);
    float* h2      = h1;  // h1 dead after conv1 aggregation
    int* cnt = cntcur;
    int* cursor = cntcur + N;

    hipMemsetAsync(cntcur, 0, (size_t)2 * N * 4, stream);

    // CSR skeleton + degree-sorted order (sort folded into single-block scan)
    count_kernel<<<(E + 255) / 256, 256, 0, stream>>>(dst, cnt, E);
    scan_kernel<<<1, 1024, 0, stream>>>(cnt, row_ptr, order, N);

    const int nodeGroups32 = (N + 31) / 32;
    // conv1
    sgemm_scores_kernel<4><<<dim3((N + 63) / 64, 4), 256, 0, stream>>>(
        x, W1, h1, N, 128, a_src1, a_dst1, s1, d1, wself1);
    fill_ew4_kernel<<<(E + 255) / 256, 256, 0, stream>>>(src, dst, row_ptr, cursor, col, pos,
                                                         s1, d1, wcsr1, E);
    gat_agg4_kernel<<<8 * nodeGroups32, 256, 0, stream>>>(h1, wcsr1, wself1, row_ptr, col,
                                                          order, b1, out1, N, E);
    // conv2
    sgemm_scores_kernel<1><<<dim3((N + 63) / 64, 1), 256, 0, stream>>>(
        out1, W2, h2, N, 256, a_src2, a_dst2, s2, d2, wself2);
    edge_w1_kernel<<<(E + 255) / 256, 256, 0, stream>>>(src, dst, pos, s2, d2, wcsr2, E);
    gat_agg1_kernel<<<2 * nodeGroups32, 256, 0, stream>>>(h2, wcsr2, wself2, row_ptr, col,
                                                          order, b2, Wlin, pn0, pn1, N);
    finalize_kernel<<<G, 64, 0, stream>>>(pn0, pn1, batch, blin, (float*)d_out, N, G);
}

// Round 8
// 231.808 us; speedup vs baseline: 1.0887x; 1.0887x over previous
//
#include <hip/hip_runtime.h>
#include <cstdint>

// GATGraphRegressor: 2-layer GAT (4-head then 1-head) + global mean pool + linear.
// Structure:
//  - Degree-sorted PERMUTED CSR: counting sort + two block scans in ONE kernel;
//    edge arrays stored in sorted-node order, each node's range padded to 4
//    (padding w=0, col=0) -> aligned int4/float4 streaming, equal-degree lanes.
//  - Edge softmax weights precomputed into [H][Epad] csr-order arrays, fused
//    into the CSR fill pass (conv1) / tiny scatter kernel (conv2).
//  - Aggregation: XCD-pinned channel slices (block b -> slice b&7; per-XCD
//    gather working set 2.56MB -> L2-resident). 8 nodes/wave, lane owns 4ch.
//  - Attention scores fused into SGEMM epilogue (each 64-col block = 1 head).

__device__ __forceinline__ float leaky02(float x) { return x > 0.f ? x : 0.2f * x; }
__device__ __forceinline__ float eluf(float x) { return x > 0.f ? x : expm1f(x); }

// ---------------- CSR count ----------------
__global__ void count_kernel(const int* __restrict__ dst, int* __restrict__ cnt, int E) {
    int e = blockIdx.x * blockDim.x + threadIdx.x;
    if (e < E) atomicAdd(&cnt[dst[e]], 1);
}

constexpr int SCAN_CHUNK = 20;  // 1024*20 = 20480 >= N=20000
// counting sort by degree -> order[]; then scan of 4-padded degrees in sorted
// order -> srow[p] (sorted row_ptr), degS[p] (actual degree), newbase[v] scatter.
__global__ __launch_bounds__(1024) void scan_sort_kernel(const int* __restrict__ cnt,
                                                         int* __restrict__ order,
                                                         int* __restrict__ srow,
                                                         int* __restrict__ degS,
                                                         int* __restrict__ newbase, int N) {
    __shared__ int lds[1024];
    __shared__ int hbin[64];
    __shared__ int binbase[64];
    const int tid = threadIdx.x;
    if (tid < 64) hbin[tid] = 0;
    __syncthreads();
    int c[SCAN_CHUNK];
    const int base = tid * SCAN_CHUNK;
#pragma unroll
    for (int i = 0; i < SCAN_CHUNK; i++) {
        int idx = base + i;
        c[i] = (idx < N) ? cnt[idx] : 0;
        if (idx < N) atomicAdd(&hbin[min(c[i], 63)], 1);
    }
    __syncthreads();
    if (tid < 64) {
        int v = hbin[tid];
        int s = v;
#pragma unroll
        for (int off = 1; off < 64; off <<= 1) {
            int o = __shfl_up(s, off);
            if (tid >= off) s += o;
        }
        binbase[tid] = s - v;
        hbin[tid] = 0;  // reuse as cursor
    }
    __syncthreads();
#pragma unroll
    for (int i = 0; i < SCAN_CHUNK; i++) {
        int idx = base + i;
        if (idx < N) {
            int b = min(c[i], 63);
            int r = atomicAdd(&hbin[b], 1);
            order[binbase[b] + r] = idx;
        }
    }
    __syncthreads();  // order[] visible block-wide
    // pass 2: scan of padded degrees in sorted order
    int da[SCAN_CHUNK];
    int loc = 0;
#pragma unroll
    for (int i = 0; i < SCAN_CHUNK; i++) {
        int idx = base + i;
        da[i] = (idx < N) ? cnt[order[idx]] : 0;
        loc += (da[i] + 3) & ~3;
    }
    lds[tid] = loc;
    __syncthreads();
    for (int off = 1; off < 1024; off <<= 1) {
        int v = (tid >= off) ? lds[tid - off] : 0;
        __syncthreads();
        lds[tid] += v;
        __syncthreads();
    }
    int run = (tid > 0) ? lds[tid - 1] : 0;
#pragma unroll
    for (int i = 0; i < SCAN_CHUNK; i++) {
        int idx = base + i;
        if (idx < N) {
            srow[idx] = run;
            degS[idx] = da[i];
            newbase[order[idx]] = run;
        }
        run += (da[i] + 3) & ~3;
    }
    if (tid == 1023) srow[N] = run;
}

// ---------------- CSR fill + conv1 edge weights ([H][Epad] layout) ----------------
__global__ void fill_ew4_kernel(const int* __restrict__ src, const int* __restrict__ dst,
                                const int* __restrict__ newbase, int* __restrict__ cursor,
                                int* __restrict__ col, int* __restrict__ pos,
                                const float* __restrict__ sS, const float* __restrict__ dS,
                                float* __restrict__ wcsr, int E, int EP) {
    int e = blockIdx.x * blockDim.x + threadIdx.x;
    if (e >= E) return;
    int s = src[e], d = dst[e];
    int p = newbase[d] + atomicAdd(&cursor[d], 1);
    col[p] = s;
    pos[e] = p;
    float4 sv = *(const float4*)&sS[s * 4];
    float4 dv = *(const float4*)&dS[d * 4];
    wcsr[p]          = __expf(leaky02(sv.x + dv.x));
    wcsr[EP + p]     = __expf(leaky02(sv.y + dv.y));
    wcsr[2 * EP + p] = __expf(leaky02(sv.z + dv.z));
    wcsr[3 * EP + p] = __expf(leaky02(sv.w + dv.w));
}

__global__ void edge_w1_kernel(const int* __restrict__ src, const int* __restrict__ dst,
                               const int* __restrict__ pos, const float* __restrict__ sS,
                               const float* __restrict__ dS, float* __restrict__ wcsr, int E) {
    int e = blockIdx.x * blockDim.x + threadIdx.x;
    if (e >= E) return;
    wcsr[pos[e]] = __expf(leaky02(sS[src[e]] + dS[dst[e]]));
}

// ---------------- SGEMM + fused per-node scores ----------------
template <int H>
__global__ __launch_bounds__(256) void sgemm_scores_kernel(
    const float* __restrict__ A, const float* __restrict__ B, float* __restrict__ C,
    int M, int K, const float* __restrict__ asrc, const float* __restrict__ adst,
    float* __restrict__ sS, float* __restrict__ dS, float* __restrict__ wself) {
    constexpr int Nc = H * 64;
    __shared__ __align__(16) float As[32][68];
    __shared__ __align__(16) float Bs[32][68];
    const int tid = threadIdx.x;
    const int bm = blockIdx.x * 64, bn = blockIdx.y * 64;
    const int ty = tid >> 4, tx = tid & 15;
    float acc[4][4] = {};
    for (int k0 = 0; k0 < K; k0 += 32) {
#pragma unroll
        for (int i = 0; i < 8; i++) {
            int idx = tid + i * 256;
            int m = idx >> 5, kk = idx & 31;
            int gm = bm + m;
            if (gm >= M) gm = 0;
            As[kk][m] = A[(size_t)gm * K + k0 + kk];
        }
#pragma unroll
        for (int i = 0; i < 8; i++) {
            int idx = tid + i * 256;
            int kk = idx >> 6, n = idx & 63;
            Bs[kk][n] = B[(size_t)(k0 + kk) * Nc + bn + n];
        }
        __syncthreads();
#pragma unroll
        for (int kk = 0; kk < 32; kk++) {
            float4 a4 = *(const float4*)&As[kk][ty * 4];
            float4 b4 = *(const float4*)&Bs[kk][tx * 4];
            float av[4] = {a4.x, a4.y, a4.z, a4.w};
            float bv[4] = {b4.x, b4.y, b4.z, b4.w};
#pragma unroll
            for (int r = 0; r < 4; r++)
#pragma unroll
                for (int c2 = 0; c2 < 4; c2++) acc[r][c2] += av[r] * bv[c2];
        }
        __syncthreads();
    }
    const int h = bn >> 6;
    float sr[4], dr[4];
#pragma unroll
    for (int r = 0; r < 4; r++) {
        float s = 0.f, d = 0.f;
#pragma unroll
        for (int c2 = 0; c2 < 4; c2++) {
            float hv = acc[r][c2];
            s += hv * asrc[h * 64 + tx * 4 + c2];
            d += hv * adst[h * 64 + tx * 4 + c2];
        }
        sr[r] = s;
        dr[r] = d;
    }
#pragma unroll
    for (int off = 1; off <= 8; off <<= 1) {
#pragma unroll
        for (int r = 0; r < 4; r++) {
            sr[r] += __shfl_xor(sr[r], off);
            dr[r] += __shfl_xor(dr[r], off);
        }
    }
#pragma unroll
    for (int r = 0; r < 4; r++) {
        int gm = bm + ty * 4 + r;
        if (gm < M) {
            float4 o = make_float4(acc[r][0], acc[r][1], acc[r][2], acc[r][3]);
            *(float4*)&C[(size_t)gm * Nc + bn + tx * 4] = o;
            if (tx == 0) {
                sS[gm * H + h] = sr[r];
                dS[gm * H + h] = dr[r];
                wself[gm * H + h] = __expf(leaky02(sr[r] + dr[r]));
            }
        }
    }
}

// ---------------- conv1 aggregation: XCD-sliced, 8 equal-degree nodes/wave ------
// Sorted CSR, 4-padded ranges -> aligned int4 col + float4 w loads, no tail logic.
__global__ __launch_bounds__(256) void gat_agg4_kernel(
    const float* __restrict__ hbuf, const float* __restrict__ wcsr,
    const float* __restrict__ wself, const int* __restrict__ srow,
    const int* __restrict__ degS, const int* __restrict__ col,
    const int* __restrict__ order, const float* __restrict__ bias,
    float* __restrict__ out, int N, int EP) {
    const int slice = blockIdx.x & 7;
    const int lane = threadIdx.x & 63;
    const int cq = lane & 7;
    const int vidx = (blockIdx.x >> 3) * 32 + (threadIdx.x >> 6) * 8 + (lane >> 3);
    const bool valid = vidx < N;
    const int vv = min(vidx, N - 1);
    const int v = order[vv];
    const int begin = srow[vv], deg = degS[vv];
    const int cbase = slice * 32 + cq * 4;
    const int hh = slice >> 1;
    const float* __restrict__ wch = wcsr + (size_t)hh * EP;
    float w = wself[v * 4 + hh];
    float den = w;
    float4 hv = *(const float4*)&hbuf[(size_t)v * 256 + cbase];
    float4 acc = make_float4(w * hv.x, w * hv.y, w * hv.z, w * hv.w);
    for (int i = begin; i < begin + deg; i += 4) {
        int4 s4 = *(const int4*)&col[i];
        float4 w4 = *(const float4*)&wch[i];
        float4 h0 = *(const float4*)&hbuf[(size_t)s4.x * 256 + cbase];
        float4 h1 = *(const float4*)&hbuf[(size_t)s4.y * 256 + cbase];
        float4 h2 = *(const float4*)&hbuf[(size_t)s4.z * 256 + cbase];
        float4 h3 = *(const float4*)&hbuf[(size_t)s4.w * 256 + cbase];
        den += w4.x + w4.y + w4.z + w4.w;
        acc.x += w4.x * h0.x + w4.y * h1.x + w4.z * h2.x + w4.w * h3.x;
        acc.y += w4.x * h0.y + w4.y * h1.y + w4.z * h2.y + w4.w * h3.y;
        acc.z += w4.x * h0.z + w4.y * h1.z + w4.z * h2.z + w4.w * h3.z;
        acc.w += w4.x * h0.w + w4.y * h1.w + w4.z * h2.w + w4.w * h3.w;
    }
    if (valid) {
        float4 b4 = *(const float4*)&bias[cbase];
        float inv = 1.f / den;
        float4 r;
        r.x = eluf(acc.x * inv + b4.x);
        r.y = eluf(acc.y * inv + b4.y);
        r.z = eluf(acc.z * inv + b4.z);
        r.w = eluf(acc.w * inv + b4.w);
        *(float4*)&out[(size_t)v * 256 + cbase] = r;
    }
}

// ---------------- conv2 aggregation (64ch) + Wlin dot, 2 slices ----------------
__global__ __launch_bounds__(256) void gat_agg1_kernel(
    const float* __restrict__ hbuf, const float* __restrict__ wcsr,
    const float* __restrict__ wself, const int* __restrict__ srow,
    const int* __restrict__ degS, const int* __restrict__ col,
    const int* __restrict__ order, const float* __restrict__ bias,
    const float* __restrict__ Wlin, float* __restrict__ pn0,
    float* __restrict__ pn1, int N) {
    const int slice = blockIdx.x & 1;
    const int lane = threadIdx.x & 63;
    const int cq = lane & 7;
    const int vidx = (blockIdx.x >> 1) * 32 + (threadIdx.x >> 6) * 8 + (lane >> 3);
    const bool valid = vidx < N;
    const int vv = min(vidx, N - 1);
    const int v = order[vv];
    const int begin = srow[vv], deg = degS[vv];
    const int cbase = slice * 32 + cq * 4;
    float w = wself[v];
    float den = w;
    float4 hv = *(const float4*)&hbuf[(size_t)v * 64 + cbase];
    float4 acc = make_float4(w * hv.x, w * hv.y, w * hv.z, w * hv.w);
    for (int i = begin; i < begin + deg; i += 4) {
        int4 s4 = *(const int4*)&col[i];
        float4 w4 = *(const float4*)&wcsr[i];
        float4 h0 = *(const float4*)&hbuf[(size_t)s4.x * 64 + cbase];
        float4 h1 = *(const float4*)&hbuf[(size_t)s4.y * 64 + cbase];
        float4 h2 = *(const float4*)&hbuf[(size_t)s4.z * 64 + cbase];
        float4 h3 = *(const float4*)&hbuf[(size_t)s4.w * 64 + cbase];
        den += w4.x + w4.y + w4.z + w4.w;
        acc.x += w4.x * h0.x + w4.y * h1.x + w4.z * h2.x + w4.w * h3.x;
        acc.y += w4.x * h0.y + w4.y * h1.y + w4.z * h2.y + w4.w * h3.y;
        acc.z += w4.x * h0.z + w4.y * h1.z + w4.z * h2.z + w4.w * h3.z;
        acc.w += w4.x * h0.w + w4.y * h1.w + w4.z * h2.w + w4.w * h3.w;
    }
    float4 b4 = *(const float4*)&bias[cbase];
    float4 wl = *(const float4*)&Wlin[cbase];
    float inv = 1.f / den;
    float p = eluf(acc.x * inv + b4.x) * wl.x + eluf(acc.y * inv + b4.y) * wl.y +
              eluf(acc.z * inv + b4.z) * wl.z + eluf(acc.w * inv + b4.w) * wl.w;
    p += __shfl_xor(p, 1);
    p += __shfl_xor(p, 2);
    p += __shfl_xor(p, 4);
    if (valid && cq == 0) (slice ? pn1 : pn0)[v] = p;
}

// ---------------- finalize: one wave per graph, segmented sum over sorted batch ----
__global__ __launch_bounds__(64) void finalize_kernel(const float* __restrict__ pn0,
                                                      const float* __restrict__ pn1,
                                                      const int* __restrict__ batch,
                                                      const float* __restrict__ blin,
                                                      float* __restrict__ outp, int N, int G) {
    const int g = blockIdx.x;
    const int lane = threadIdx.x;
    int lo = 0, hi = N;
    while (lo < hi) { int mid = (lo + hi) >> 1; if (batch[mid] < g) lo = mid + 1; else hi = mid; }
    int lo2 = lo, hi2 = N;
    while (lo2 < hi2) { int mid = (lo2 + hi2) >> 1; if (batch[mid] < g + 1) lo2 = mid + 1; else hi2 = mid; }
    float s = 0.f;
    for (int i = lo + lane; i < hi2; i += 64) s += pn0[i] + pn1[i];
#pragma unroll
    for (int off = 32; off > 0; off >>= 1) s += __shfl_xor(s, off);
    if (lane == 0) {
        float cnt = (float)(hi2 - lo);
        outp[g] = s / fmaxf(cnt, 1.f) + blin[0];
    }
}

extern "C" void kernel_launch(void* const* d_in, const int* in_sizes, int n_in,
                              void* d_out, int out_size, void* d_ws, size_t ws_size,
                              hipStream_t stream) {
    const float* x      = (const float*)d_in[0];
    const int*   ei     = (const int*)d_in[1];
    const int*   batch  = (const int*)d_in[2];
    const float* W1     = (const float*)d_in[3];
    const float* a_src1 = (const float*)d_in[4];
    const float* a_dst1 = (const float*)d_in[5];
    const float* b1     = (const float*)d_in[6];
    const float* W2     = (const float*)d_in[7];
    const float* a_src2 = (const float*)d_in[8];
    const float* a_dst2 = (const float*)d_in[9];
    const float* b2     = (const float*)d_in[10];
    const float* Wlin   = (const float*)d_in[11];
    const float* blin   = (const float*)d_in[12];

    const int N = in_sizes[2];
    const int E = in_sizes[1] / 2;
    const int G = out_size;
    const int EP = (E + 3 * N + 16 + 3) & ~3;  // padded edge capacity (each node +<=3)
    const int* src = ei;
    const int* dst = ei + E;

    char* ws = (char*)d_ws;
    size_t off = 0;
    auto carve = [&](size_t bytes) -> char* {
        char* p = ws + off;
        off = (off + bytes + 255) & ~(size_t)255;
        return p;
    };
    float* h1      = (float*)carve((size_t)N * 256 * 4);
    float* out1    = (float*)carve((size_t)N * 256 * 4);
    float* s1      = (float*)carve((size_t)N * 4 * 4);
    float* d1      = (float*)carve((size_t)N * 4 * 4);
    float* wself1  = (float*)carve((size_t)N * 4 * 4);
    float* s2      = (float*)carve((size_t)N * 4);
    float* d2      = (float*)carve((size_t)N * 4);
    float* wself2  = (float*)carve((size_t)N * 4);
    int*   srow    = (int*)carve((size_t)(N + 1) * 4);
    int*   degS    = (int*)carve((size_t)N * 4);
    int*   newbase = (int*)carve((size_t)N * 4);
    int*   cntcur  = (int*)carve((size_t)2 * N * 4);
    int*   col     = (int*)carve((size_t)EP * 4);
    int*   pos     = (int*)carve((size_t)E * 4);
    float* wcsr1   = (float*)carve((size_t)EP * 4 * 4);  // [H][EP]
    float* wcsr2   = (float*)carve((size_t)EP * 4);
    int*   order   = (int*)carve((size_t)N * 4);
    float* pn0     = (float*)carve((size_t)N * 4);
    float* pn1     = (float*)carve((size_t)N * 4);
    float* h2      = h1;  // h1 dead after conv1 aggregation
    int* cnt = cntcur;
    int* cursor = cntcur + N;

    hipMemsetAsync(cntcur, 0, (size_t)2 * N * 4, stream);
    hipMemsetAsync(col, 0, (size_t)EP * 4, stream);       // padding -> node 0
    hipMemsetAsync(wcsr1, 0, (size_t)EP * 4 * 4, stream); // padding -> w=0
    hipMemsetAsync(wcsr2, 0, (size_t)EP * 4, stream);

    // CSR skeleton in degree-sorted order
    count_kernel<<<(E + 255) / 256, 256, 0, stream>>>(dst, cnt, E);
    scan_sort_kernel<<<1, 1024, 0, stream>>>(cnt, order, srow, degS, newbase, N);

    const int nodeGroups32 = (N + 31) / 32;
    // conv1
    sgemm_scores_kernel<4><<<dim3((N + 63) / 64, 4), 256, 0, stream>>>(
        x, W1, h1, N, 128, a_src1, a_dst1, s1, d1, wself1);
    fill_ew4_kernel<<<(E + 255) / 256, 256, 0, stream>>>(src, dst, newbase, cursor, col, pos,
                                                         s1, d1, wcsr1, E, EP);
    gat_agg4_kernel<<<8 * nodeGroups32, 256, 0, stream>>>(h1, wcsr1, wself1, srow, degS, col,
                                                          order, b1, out1, N, EP);
    // conv2
    sgemm_scores_kernel<1><<<dim3((N + 63) / 64, 1), 256, 0, stream>>>(
        out1, W2, h2, N, 256, a_src2, a_dst2, s2, d2, wself2);
    edge_w1_kernel<<<(E + 255) / 256, 256, 0, stream>>>(src, dst, pos, s2, d2, wcsr2, E);
    gat_agg1_kernel<<<2 * nodeGroups32, 256, 0, stream>>>(h2, wcsr2, wself2, srow, degS, col,
                                                          order, b2, Wlin, pn0, pn1, N);
    finalize_kernel<<<G, 64, 0, stream>>>(pn0, pn1, batch, blin, (float*)d_out, N, G);
}

// Round 9
// 174.548 us; speedup vs baseline: 1.4459x; 1.3280x over previous
//
#include <hip/hip_runtime.h>
#include <cstdint>

// GATGraphRegressor: 2-layer GAT (4-head then 1-head) + global mean pool + linear.
// Structure:
//  - 4-padded CSR in NATURAL node order (no degree sort: the single-block sort
//    kernel cost 68us to save ~8us of divergence). Padding (w=0,col=0) gives
//    aligned int4/float4 streaming with zero tail logic.
//  - Edge softmax weights precomputed into [H][Epad] csr-order arrays, fused
//    into the CSR fill pass (conv1) / tiny scatter kernel (conv2).
//  - Aggregation: XCD-pinned channel slices (block b -> slice b&7; per-XCD
//    gather working set 2.56MB -> L2-resident). 8 nodes/wave, lane owns 4ch.
//  - Attention scores fused into SGEMM epilogue (each 64-col block = 1 head).
//  - One fused memset over a contiguous scratch region (fewer dispatches).

__device__ __forceinline__ float leaky02(float x) { return x > 0.f ? x : 0.2f * x; }
__device__ __forceinline__ float eluf(float x) { return x > 0.f ? x : expm1f(x); }

// ---------------- CSR count ----------------
__global__ void count_kernel(const int* __restrict__ dst, int* __restrict__ cnt, int E) {
    int e = blockIdx.x * blockDim.x + threadIdx.x;
    if (e < E) atomicAdd(&cnt[dst[e]], 1);
}

constexpr int SCAN_CHUNK = 20;  // 1024*20 = 20480 >= N=20000
// scan of 4-padded degrees (natural order) -> srow[v]; srow[N] = padded total.
__global__ __launch_bounds__(1024) void scan_kernel(const int* __restrict__ cnt,
                                                    int* __restrict__ srow, int N) {
    __shared__ int lds[1024];
    const int tid = threadIdx.x;
    int c[SCAN_CHUNK];
    const int base = tid * SCAN_CHUNK;
    int loc = 0;
#pragma unroll
    for (int i = 0; i < SCAN_CHUNK; i++) {
        int idx = base + i;
        c[i] = (idx < N) ? cnt[idx] : 0;
        loc += (c[i] + 3) & ~3;
    }
    lds[tid] = loc;
    __syncthreads();
    for (int off = 1; off < 1024; off <<= 1) {
        int v = (tid >= off) ? lds[tid - off] : 0;
        __syncthreads();
        lds[tid] += v;
        __syncthreads();
    }
    int run = (tid > 0) ? lds[tid - 1] : 0;
#pragma unroll
    for (int i = 0; i < SCAN_CHUNK; i++) {
        int idx = base + i;
        if (idx < N) srow[idx] = run;
        run += (c[i] + 3) & ~3;
    }
    if (tid == 1023) srow[N] = run;
}

// ---------------- CSR fill + conv1 edge weights ([H][Epad] layout) ----------------
__global__ void fill_ew4_kernel(const int* __restrict__ src, const int* __restrict__ dst,
                                const int* __restrict__ srow, int* __restrict__ cursor,
                                int* __restrict__ col, int* __restrict__ pos,
                                const float* __restrict__ sS, const float* __restrict__ dS,
                                float* __restrict__ wcsr, int E, int EP) {
    int e = blockIdx.x * blockDim.x + threadIdx.x;
    if (e >= E) return;
    int s = src[e], d = dst[e];
    int p = srow[d] + atomicAdd(&cursor[d], 1);
    col[p] = s;
    pos[e] = p;
    float4 sv = *(const float4*)&sS[s * 4];
    float4 dv = *(const float4*)&dS[d * 4];
    wcsr[p]          = __expf(leaky02(sv.x + dv.x));
    wcsr[EP + p]     = __expf(leaky02(sv.y + dv.y));
    wcsr[2 * EP + p] = __expf(leaky02(sv.z + dv.z));
    wcsr[3 * EP + p] = __expf(leaky02(sv.w + dv.w));
}

__global__ void edge_w1_kernel(const int* __restrict__ src, const int* __restrict__ dst,
                               const int* __restrict__ pos, const float* __restrict__ sS,
                               const float* __restrict__ dS, float* __restrict__ wcsr, int E) {
    int e = blockIdx.x * blockDim.x + threadIdx.x;
    if (e >= E) return;
    wcsr[pos[e]] = __expf(leaky02(sS[src[e]] + dS[dst[e]]));
}

// ---------------- SGEMM + fused per-node scores ----------------
template <int H>
__global__ __launch_bounds__(256) void sgemm_scores_kernel(
    const float* __restrict__ A, const float* __restrict__ B, float* __restrict__ C,
    int M, int K, const float* __restrict__ asrc, const float* __restrict__ adst,
    float* __restrict__ sS, float* __restrict__ dS, float* __restrict__ wself) {
    constexpr int Nc = H * 64;
    __shared__ __align__(16) float As[32][68];
    __shared__ __align__(16) float Bs[32][68];
    const int tid = threadIdx.x;
    const int bm = blockIdx.x * 64, bn = blockIdx.y * 64;
    const int ty = tid >> 4, tx = tid & 15;
    float acc[4][4] = {};
    for (int k0 = 0; k0 < K; k0 += 32) {
#pragma unroll
        for (int i = 0; i < 8; i++) {
            int idx = tid + i * 256;
            int m = idx >> 5, kk = idx & 31;
            int gm = bm + m;
            if (gm >= M) gm = 0;
            As[kk][m] = A[(size_t)gm * K + k0 + kk];
        }
#pragma unroll
        for (int i = 0; i < 8; i++) {
            int idx = tid + i * 256;
            int kk = idx >> 6, n = idx & 63;
            Bs[kk][n] = B[(size_t)(k0 + kk) * Nc + bn + n];
        }
        __syncthreads();
#pragma unroll
        for (int kk = 0; kk < 32; kk++) {
            float4 a4 = *(const float4*)&As[kk][ty * 4];
            float4 b4 = *(const float4*)&Bs[kk][tx * 4];
            float av[4] = {a4.x, a4.y, a4.z, a4.w};
            float bv[4] = {b4.x, b4.y, b4.z, b4.w};
#pragma unroll
            for (int r = 0; r < 4; r++)
#pragma unroll
                for (int c2 = 0; c2 < 4; c2++) acc[r][c2] += av[r] * bv[c2];
        }
        __syncthreads();
    }
    const int h = bn >> 6;
    float sr[4], dr[4];
#pragma unroll
    for (int r = 0; r < 4; r++) {
        float s = 0.f, d = 0.f;
#pragma unroll
        for (int c2 = 0; c2 < 4; c2++) {
            float hv = acc[r][c2];
            s += hv * asrc[h * 64 + tx * 4 + c2];
            d += hv * adst[h * 64 + tx * 4 + c2];
        }
        sr[r] = s;
        dr[r] = d;
    }
#pragma unroll
    for (int off = 1; off <= 8; off <<= 1) {
#pragma unroll
        for (int r = 0; r < 4; r++) {
            sr[r] += __shfl_xor(sr[r], off);
            dr[r] += __shfl_xor(dr[r], off);
        }
    }
#pragma unroll
    for (int r = 0; r < 4; r++) {
        int gm = bm + ty * 4 + r;
        if (gm < M) {
            float4 o = make_float4(acc[r][0], acc[r][1], acc[r][2], acc[r][3]);
            *(float4*)&C[(size_t)gm * Nc + bn + tx * 4] = o;
            if (tx == 0) {
                sS[gm * H + h] = sr[r];
                dS[gm * H + h] = dr[r];
                wself[gm * H + h] = __expf(leaky02(sr[r] + dr[r]));
            }
        }
    }
}

// ---------------- conv1 aggregation: XCD-sliced, 8 nodes/wave ----------------
// Natural-order padded CSR -> aligned int4 col + float4 w loads, no tail logic.
__global__ __launch_bounds__(256) void gat_agg4_kernel(
    const float* __restrict__ hbuf, const float* __restrict__ wcsr,
    const float* __restrict__ wself, const int* __restrict__ srow,
    const int* __restrict__ deg, const int* __restrict__ col,
    const float* __restrict__ bias, float* __restrict__ out, int N, int EP) {
    const int slice = blockIdx.x & 7;
    const int lane = threadIdx.x & 63;
    const int cq = lane & 7;
    const int vidx = (blockIdx.x >> 3) * 32 + (threadIdx.x >> 6) * 8 + (lane >> 3);
    const bool valid = vidx < N;
    const int v = min(vidx, N - 1);
    const int begin = srow[v], dg = deg[v];
    const int cbase = slice * 32 + cq * 4;
    const int hh = slice >> 1;
    const float* __restrict__ wch = wcsr + (size_t)hh * EP;
    float w = wself[v * 4 + hh];
    float den = w;
    float4 hv = *(const float4*)&hbuf[(size_t)v * 256 + cbase];
    float4 acc = make_float4(w * hv.x, w * hv.y, w * hv.z, w * hv.w);
    for (int i = begin; i < begin + dg; i += 4) {
        int4 s4 = *(const int4*)&col[i];
        float4 w4 = *(const float4*)&wch[i];
        float4 h0 = *(const float4*)&hbuf[(size_t)s4.x * 256 + cbase];
        float4 h1 = *(const float4*)&hbuf[(size_t)s4.y * 256 + cbase];
        float4 h2 = *(const float4*)&hbuf[(size_t)s4.z * 256 + cbase];
        float4 h3 = *(const float4*)&hbuf[(size_t)s4.w * 256 + cbase];
        den += w4.x + w4.y + w4.z + w4.w;
        acc.x += w4.x * h0.x + w4.y * h1.x + w4.z * h2.x + w4.w * h3.x;
        acc.y += w4.x * h0.y + w4.y * h1.y + w4.z * h2.y + w4.w * h3.y;
        acc.z += w4.x * h0.z + w4.y * h1.z + w4.z * h2.z + w4.w * h3.z;
        acc.w += w4.x * h0.w + w4.y * h1.w + w4.z * h2.w + w4.w * h3.w;
    }
    if (valid) {
        float4 b4 = *(const float4*)&bias[cbase];
        float inv = 1.f / den;
        float4 r;
        r.x = eluf(acc.x * inv + b4.x);
        r.y = eluf(acc.y * inv + b4.y);
        r.z = eluf(acc.z * inv + b4.z);
        r.w = eluf(acc.w * inv + b4.w);
        *(float4*)&out[(size_t)v * 256 + cbase] = r;
    }
}

// ---------------- conv2 aggregation (64ch) + Wlin dot, 2 slices ----------------
__global__ __launch_bounds__(256) void gat_agg1_kernel(
    const float* __restrict__ hbuf, const float* __restrict__ wcsr,
    const float* __restrict__ wself, const int* __restrict__ srow,
    const int* __restrict__ deg, const int* __restrict__ col,
    const float* __restrict__ bias, const float* __restrict__ Wlin,
    float* __restrict__ pn0, float* __restrict__ pn1, int N) {
    const int slice = blockIdx.x & 1;
    const int lane = threadIdx.x & 63;
    const int cq = lane & 7;
    const int vidx = (blockIdx.x >> 1) * 32 + (threadIdx.x >> 6) * 8 + (lane >> 3);
    const bool valid = vidx < N;
    const int v = min(vidx, N - 1);
    const int begin = srow[v], dg = deg[v];
    const int cbase = slice * 32 + cq * 4;
    float w = wself[v];
    float den = w;
    float4 hv = *(const float4*)&hbuf[(size_t)v * 64 + cbase];
    float4 acc = make_float4(w * hv.x, w * hv.y, w * hv.z, w * hv.w);
    for (int i = begin; i < begin + dg; i += 4) {
        int4 s4 = *(const int4*)&col[i];
        float4 w4 = *(const float4*)&wcsr[i];
        float4 h0 = *(const float4*)&hbuf[(size_t)s4.x * 64 + cbase];
        float4 h1 = *(const float4*)&hbuf[(size_t)s4.y * 64 + cbase];
        float4 h2 = *(const float4*)&hbuf[(size_t)s4.z * 64 + cbase];
        float4 h3 = *(const float4*)&hbuf[(size_t)s4.w * 64 + cbase];
        den += w4.x + w4.y + w4.z + w4.w;
        acc.x += w4.x * h0.x + w4.y * h1.x + w4.z * h2.x + w4.w * h3.x;
        acc.y += w4.x * h0.y + w4.y * h1.y + w4.z * h2.y + w4.w * h3.y;
        acc.z += w4.x * h0.z + w4.y * h1.z + w4.z * h2.z + w4.w * h3.z;
        acc.w += w4.x * h0.w + w4.y * h1.w + w4.z * h2.w + w4.w * h3.w;
    }
    float4 b4 = *(const float4*)&bias[cbase];
    float4 wl = *(const float4*)&Wlin[cbase];
    float inv = 1.f / den;
    float p = eluf(acc.x * inv + b4.x) * wl.x + eluf(acc.y * inv + b4.y) * wl.y +
              eluf(acc.z * inv + b4.z) * wl.z + eluf(acc.w * inv + b4.w) * wl.w;
    p += __shfl_xor(p, 1);
    p += __shfl_xor(p, 2);
    p += __shfl_xor(p, 4);
    if (valid && cq == 0) (slice ? pn1 : pn0)[v] = p;
}

// ---------------- finalize: one wave per graph, segmented sum over sorted batch ----
__global__ __launch_bounds__(64) void finalize_kernel(const float* __restrict__ pn0,
                                                      const float* __restrict__ pn1,
                                                      const int* __restrict__ batch,
                                                      const float* __restrict__ blin,
                                                      float* __restrict__ outp, int N, int G) {
    const int g = blockIdx.x;
    const int lane = threadIdx.x;
    int lo = 0, hi = N;
    while (lo < hi) { int mid = (lo + hi) >> 1; if (batch[mid] < g) lo = mid + 1; else hi = mid; }
    int lo2 = lo, hi2 = N;
    while (lo2 < hi2) { int mid = (lo2 + hi2) >> 1; if (batch[mid] < g + 1) lo2 = mid + 1; else hi2 = mid; }
    float s = 0.f;
    for (int i = lo + lane; i < hi2; i += 64) s += pn0[i] + pn1[i];
#pragma unroll
    for (int off = 32; off > 0; off >>= 1) s += __shfl_xor(s, off);
    if (lane == 0) {
        float cnt = (float)(hi2 - lo);
        outp[g] = s / fmaxf(cnt, 1.f) + blin[0];
    }
}

extern "C" void kernel_launch(void* const* d_in, const int* in_sizes, int n_in,
                              void* d_out, int out_size, void* d_ws, size_t ws_size,
                              hipStream_t stream) {
    const float* x      = (const float*)d_in[0];
    const int*   ei     = (const int*)d_in[1];
    const int*   batch  = (const int*)d_in[2];
    const float* W1     = (const float*)d_in[3];
    const float* a_src1 = (const float*)d_in[4];
    const float* a_dst1 = (const float*)d_in[5];
    const float* b1     = (const float*)d_in[6];
    const float* W2     = (const float*)d_in[7];
    const float* a_src2 = (const float*)d_in[8];
    const float* a_dst2 = (const float*)d_in[9];
    const float* b2     = (const float*)d_in[10];
    const float* Wlin   = (const float*)d_in[11];
    const float* blin   = (const float*)d_in[12];

    const int N = in_sizes[2];
    const int E = in_sizes[1] / 2;
    const int G = out_size;
    const int EP = (E + 3 * N + 16 + 3) & ~3;  // padded edge capacity
    const int* src = ei;
    const int* dst = ei + E;

    char* ws = (char*)d_ws;
    size_t off = 0;
    auto carve = [&](size_t bytes) -> char* {
        char* p = ws + off;
        off = (off + bytes + 255) & ~(size_t)255;
        return p;
    };
    float* h1      = (float*)carve((size_t)N * 256 * 4);
    float* out1    = (float*)carve((size_t)N * 256 * 4);
    float* s1      = (float*)carve((size_t)N * 4 * 4);
    float* d1      = (float*)carve((size_t)N * 4 * 4);
    float* wself1  = (float*)carve((size_t)N * 4 * 4);
    float* s2      = (float*)carve((size_t)N * 4);
    float* d2      = (float*)carve((size_t)N * 4);
    float* wself2  = (float*)carve((size_t)N * 4);
    int*   srow    = (int*)carve((size_t)(N + 1) * 4);
    int*   pos     = (int*)carve((size_t)E * 4);
    // ---- zeroed region (single memset): cnt | cursor | col | wcsr1 | wcsr2 ----
    size_t zero_begin = off;
    int*   cntcur  = (int*)carve((size_t)2 * N * 4);
    int*   col     = (int*)carve((size_t)EP * 4);
    float* wcsr1   = (float*)carve((size_t)EP * 4 * 4);  // [H][EP]
    float* wcsr2   = (float*)carve((size_t)EP * 4);
    size_t zero_end = off;
    // ---------------------------------------------------------------
    float* pn0     = (float*)carve((size_t)N * 4);
    float* pn1     = (float*)carve((size_t)N * 4);
    float* h2      = h1;  // h1 dead after conv1 aggregation
    int* cnt = cntcur;
    int* cursor = cntcur + N;

    hipMemsetAsync(ws + zero_begin, 0, zero_end - zero_begin, stream);

    // CSR skeleton (natural order, 4-padded)
    count_kernel<<<(E + 255) / 256, 256, 0, stream>>>(dst, cnt, E);
    scan_kernel<<<1, 1024, 0, stream>>>(cnt, srow, N);

    const int nodeGroups32 = (N + 31) / 32;
    // conv1
    sgemm_scores_kernel<4><<<dim3((N + 63) / 64, 4), 256, 0, stream>>>(
        x, W1, h1, N, 128, a_src1, a_dst1, s1, d1, wself1);
    fill_ew4_kernel<<<(E + 255) / 256, 256, 0, stream>>>(src, dst, srow, cursor, col, pos,
                                                         s1, d1, wcsr1, E, EP);
    gat_agg4_kernel<<<8 * nodeGroups32, 256, 0, stream>>>(h1, wcsr1, wself1, srow, cnt, col,
                                                          b1, out1, N, EP);
    // conv2
    sgemm_scores_kernel<1><<<dim3((N + 63) / 64, 1), 256, 0, stream>>>(
        out1, W2, h2, N, 256, a_src2, a_dst2, s2, d2, wself2);
    edge_w1_kernel<<<(E + 255) / 256, 256, 0, stream>>>(src, dst, pos, s2, d2, wcsr2, E);
    gat_agg1_kernel<<<2 * nodeGroups32, 256, 0, stream>>>(h2, wcsr2, wself2, srow, cnt, col,
                                                          b2, Wlin, pn0, pn1, N);
    finalize_kernel<<<G, 64, 0, stream>>>(pn0, pn1, batch, blin, (float*)d_out, N, G);
}